// Round 1
// baseline (185.224 us; speedup 1.0000x reference)
//
#include <hip/hip_runtime.h>
#include <hip/hip_fp16.h>

#define BATCH 8
#define SEQ   1024
#define DIM   512
#define HEADS 8
#define DHEAD 64
#define MTOT  (BATCH*SEQ)   // 8192

typedef _Float16 f16x8 __attribute__((ext_vector_type(8)));
typedef _Float16 f16x4 __attribute__((ext_vector_type(4)));
typedef float    fx4   __attribute__((ext_vector_type(4)));

#define MFMA16 __builtin_amdgcn_mfma_f32_16x16x32_f16

// ---------------------------------------------------------------------------
// Kernel 0: fp32 -> fp16 conversion (x, wq|wk|wv concat, wo)
// ---------------------------------------------------------------------------
__global__ __launch_bounds__(256) void convert_k(
    const float* __restrict__ x,  const float* __restrict__ wq,
    const float* __restrict__ wk, const float* __restrict__ wv,
    const float* __restrict__ wo,
    _Float16* __restrict__ xb, _Float16* __restrict__ wqkvb,
    _Float16* __restrict__ wob)
{
    const int XU = (MTOT*DIM)/4;   // 1048576 float4 units
    const int WU = (DIM*DIM)/4;    // 65536 units per weight
    int idx = blockIdx.x*256 + threadIdx.x;
    if (idx >= XU + 4*WU) return;
    const float* src; _Float16* dst;
    if (idx < XU) { src = x + idx*4; dst = xb + idx*4; }
    else {
        int t = idx - XU; int region = t >> 16; int off = (t & 65535)*4;
        if      (region == 0) { src = wq + off; dst = wqkvb + off; }
        else if (region == 1) { src = wk + off; dst = wqkvb + DIM*DIM + off; }
        else if (region == 2) { src = wv + off; dst = wqkvb + 2*DIM*DIM + off; }
        else                  { src = wo + off; dst = wob + off; }
    }
    float4 v = *(const float4*)src;
    f16x4 o = { (_Float16)v.x, (_Float16)v.y, (_Float16)v.z, (_Float16)v.w };
    *(f16x4*)dst = o;
}

// ---------------------------------------------------------------------------
// Kernel 1: fused QKV projection GEMM  (M=8192, N=1536, K=512), A@B^T
// Epilogue: Q scaled by 0.125 -> [b,h,n,d]; K -> [b,h,n,d]; V -> [b,h,d,n]
// ---------------------------------------------------------------------------
__global__ __launch_bounds__(256,2) void qkv_proj(
    const _Float16* __restrict__ A, const _Float16* __restrict__ B,
    _Float16* __restrict__ Qb, _Float16* __restrict__ Kb,
    _Float16* __restrict__ VTb)
{
    __shared__ _Float16 lA[128*72];
    __shared__ _Float16 lB[128*72];
    const int tid = threadIdx.x;
    const int m0 = blockIdx.y*128, n0 = blockIdx.x*128;
    const int w = tid>>6, l = tid&63, lr = l&15, lq = l>>4;
    const int wr = w>>1, wc = w&1;
    fx4 acc[4][4] = {};

    for (int k0 = 0; k0 < DIM; k0 += 64) {
        __syncthreads();
#pragma unroll
        for (int i = 0; i < 4; i++) {
            int u = tid + i*256;            // 1024 16B-units per tile
            int row = u >> 3, cu = (u & 7)*8;
            *(f16x8*)&lA[row*72 + cu] = *(const f16x8*)&A[(m0+row)*DIM + k0 + cu];
            *(f16x8*)&lB[row*72 + cu] = *(const f16x8*)&B[(n0+row)*DIM + k0 + cu];
        }
        __syncthreads();
#pragma unroll
        for (int kb = 0; kb < 2; kb++) {
            f16x8 af[4], bf[4];
#pragma unroll
            for (int cb = 0; cb < 4; cb++)
                bf[cb] = *(const f16x8*)&lB[(wc*64+cb*16+lr)*72 + kb*32 + lq*8];
#pragma unroll
            for (int rb = 0; rb < 4; rb++)
                af[rb] = *(const f16x8*)&lA[(wr*64+rb*16+lr)*72 + kb*32 + lq*8];
#pragma unroll
            for (int rb = 0; rb < 4; rb++)
#pragma unroll
                for (int cb = 0; cb < 4; cb++)
                    acc[rb][cb] = MFMA16(af[rb], bf[cb], acc[rb][cb], 0,0,0);
        }
    }
#pragma unroll
    for (int rb = 0; rb < 4; rb++)
#pragma unroll
        for (int cb = 0; cb < 4; cb++) {
            int nn = n0 + wc*64 + cb*16 + lr;
            int which = nn >> 9, inner = nn & 511, h = inner >> 6, d = inner & 63;
#pragma unroll
            for (int i = 0; i < 4; i++) {
                int m = m0 + wr*64 + rb*16 + lq*4 + i;
                int b = m >> 10, n = m & 1023;
                float v = acc[rb][cb][i];
                if (which == 0)
                    Qb[((b*HEADS+h)*SEQ + n)*DHEAD + d] = (_Float16)(v * 0.125f);
                else if (which == 1)
                    Kb[((b*HEADS+h)*SEQ + n)*DHEAD + d] = (_Float16)v;
                else
                    VTb[((b*HEADS+h)*DHEAD + d)*SEQ + n] = (_Float16)v;
            }
        }
}

// ---------------------------------------------------------------------------
// Kernel 2: attention per (b,h). 128 Q-rows per block, K/V tiles of 128.
// S = Q·K^T (scale folded into Q); P = exp(clip(S,1e-6,1)); O = P·V / rowsum.
// ---------------------------------------------------------------------------
__global__ __launch_bounds__(256,2) void attn_k(
    const _Float16* __restrict__ Q, const _Float16* __restrict__ K,
    const _Float16* __restrict__ VT, _Float16* __restrict__ AO)
{
    __shared__ _Float16 lKV[128*72];        // K tile [128][72] / VT tile [64][136]
    __shared__ _Float16 lP[4][32*136];      // per-wave P tile [32][136]
    const int tid = threadIdx.x;
    const int w = tid>>6, l = tid&63, lr = l&15, lq = l>>4;
    const int bh = blockIdx.y, q0 = blockIdx.x*128;
    const int b = bh>>3, h = bh&7;
    const _Float16* Qp = Q  + (size_t)bh*SEQ*DHEAD;
    const _Float16* Kp = K  + (size_t)bh*SEQ*DHEAD;
    const _Float16* Vp = VT + (size_t)bh*DHEAD*SEQ;

    f16x8 qf[2][2];
#pragma unroll
    for (int r = 0; r < 2; r++)
#pragma unroll
        for (int kb = 0; kb < 2; kb++)
            qf[r][kb] = *(const f16x8*)&Qp[(q0 + w*32 + r*16 + lr)*DHEAD + kb*32 + lq*8];

    fx4 O[2][4] = {};
    fx4 lsum[2] = {};

    for (int kt = 0; kt < 8; kt++) {
        int k0 = kt*128;
        __syncthreads();
#pragma unroll
        for (int i = 0; i < 4; i++) {        // stage K tile [128][64]
            int u = tid + i*256;
            int row = u >> 3, cu = (u & 7)*8;
            *(f16x8*)&lKV[row*72 + cu] = *(const f16x8*)&Kp[(k0+row)*DHEAD + cu];
        }
        __syncthreads();
        // ---- S = Q K^T, clip, exp, write P to LDS, accumulate rowsum ----
#pragma unroll
        for (int cb = 0; cb < 8; cb++) {
            f16x8 kf[2];
#pragma unroll
            for (int kb = 0; kb < 2; kb++)
                kf[kb] = *(const f16x8*)&lKV[(cb*16+lr)*72 + kb*32 + lq*8];
#pragma unroll
            for (int r = 0; r < 2; r++) {
                fx4 s = {};
                s = MFMA16(qf[r][0], kf[0], s, 0,0,0);
                s = MFMA16(qf[r][1], kf[1], s, 0,0,0);
#pragma unroll
                for (int i = 0; i < 4; i++) {
                    float p = __expf(fminf(fmaxf(s[i], 1e-6f), 1.0f));
                    lsum[r][i] += p;
                    lP[w][(r*16 + lq*4 + i)*136 + cb*16 + lr] = (_Float16)p;
                }
            }
        }
        __syncthreads();
#pragma unroll
        for (int i = 0; i < 4; i++) {        // stage V^T tile [64][128]
            int u = tid + i*256;
            int row = u >> 4, cu = (u & 15)*8;
            *(f16x8*)&lKV[row*136 + cu] = *(const f16x8*)&Vp[row*SEQ + k0 + cu];
        }
        __syncthreads();
        // ---- O += P V ----
#pragma unroll
        for (int ks = 0; ks < 4; ks++) {
            f16x8 af[2];
#pragma unroll
            for (int r = 0; r < 2; r++)
                af[r] = *(const f16x8*)&lP[w][(r*16+lr)*136 + ks*32 + lq*8];
#pragma unroll
            for (int db = 0; db < 4; db++) {
                f16x8 vf = *(const f16x8*)&lKV[(db*16+lr)*136 + ks*32 + lq*8];
                O[0][db] = MFMA16(af[0], vf, O[0][db], 0,0,0);
                O[1][db] = MFMA16(af[1], vf, O[1][db], 0,0,0);
            }
        }
    }
    // rowsum reduction across the 16 col-lanes
#pragma unroll
    for (int r = 0; r < 2; r++)
#pragma unroll
        for (int i = 0; i < 4; i++) {
            float s = lsum[r][i];
            s += __shfl_xor(s, 1);
            s += __shfl_xor(s, 2);
            s += __shfl_xor(s, 4);
            s += __shfl_xor(s, 8);
            lsum[r][i] = s;
        }
#pragma unroll
    for (int r = 0; r < 2; r++) {
        fx4 inv;
#pragma unroll
        for (int i = 0; i < 4; i++) inv[i] = 1.0f / lsum[r][i];
#pragma unroll
        for (int db = 0; db < 4; db++)
#pragma unroll
            for (int i = 0; i < 4; i++) {
                int n = q0 + w*32 + r*16 + lq*4 + i;
                int d = db*16 + lr;
                AO[((size_t)(b*SEQ + n)*HEADS + h)*DHEAD + d] =
                    (_Float16)(O[r][db][i] * inv[i]);
            }
    }
}

// ---------------------------------------------------------------------------
// Kernel 3: output projection  out = AO @ wo^T + bo   (M=8192, N=512, K=512)
// ---------------------------------------------------------------------------
__global__ __launch_bounds__(256,2) void out_proj(
    const _Float16* __restrict__ A, const _Float16* __restrict__ B,
    const float* __restrict__ bo, float* __restrict__ out)
{
    __shared__ _Float16 lA[128*72];
    __shared__ _Float16 lB[128*72];
    const int tid = threadIdx.x;
    const int m0 = blockIdx.y*128, n0 = blockIdx.x*128;
    const int w = tid>>6, l = tid&63, lr = l&15, lq = l>>4;
    const int wr = w>>1, wc = w&1;
    fx4 acc[4][4] = {};

    for (int k0 = 0; k0 < DIM; k0 += 64) {
        __syncthreads();
#pragma unroll
        for (int i = 0; i < 4; i++) {
            int u = tid + i*256;
            int row = u >> 3, cu = (u & 7)*8;
            *(f16x8*)&lA[row*72 + cu] = *(const f16x8*)&A[(m0+row)*DIM + k0 + cu];
            *(f16x8*)&lB[row*72 + cu] = *(const f16x8*)&B[(n0+row)*DIM + k0 + cu];
        }
        __syncthreads();
#pragma unroll
        for (int kb = 0; kb < 2; kb++) {
            f16x8 af[4], bf[4];
#pragma unroll
            for (int cb = 0; cb < 4; cb++)
                bf[cb] = *(const f16x8*)&lB[(wc*64+cb*16+lr)*72 + kb*32 + lq*8];
#pragma unroll
            for (int rb = 0; rb < 4; rb++)
                af[rb] = *(const f16x8*)&lA[(wr*64+rb*16+lr)*72 + kb*32 + lq*8];
#pragma unroll
            for (int rb = 0; rb < 4; rb++)
#pragma unroll
                for (int cb = 0; cb < 4; cb++)
                    acc[rb][cb] = MFMA16(af[rb], bf[cb], acc[rb][cb], 0,0,0);
        }
    }
#pragma unroll
    for (int rb = 0; rb < 4; rb++)
#pragma unroll
        for (int cb = 0; cb < 4; cb++) {
            int nn = n0 + wc*64 + cb*16 + lr;
            float bias = bo[nn];
#pragma unroll
            for (int i = 0; i < 4; i++) {
                int m = m0 + wr*64 + rb*16 + lq*4 + i;
                out[(size_t)m*DIM + nn] = acc[rb][cb][i] + bias;
            }
        }
}

// ---------------------------------------------------------------------------
extern "C" void kernel_launch(void* const* d_in, const int* in_sizes, int n_in,
                              void* d_out, int out_size, void* d_ws, size_t ws_size,
                              hipStream_t stream)
{
    const float* x  = (const float*)d_in[0];
    const float* wq = (const float*)d_in[1];
    const float* wk = (const float*)d_in[2];
    const float* wv = (const float*)d_in[3];
    const float* wo = (const float*)d_in[4];
    const float* bo = (const float*)d_in[5];
    float* out = (float*)d_out;
    char* ws = (char*)d_ws;

    // workspace layout (bytes):
    _Float16* xb    = (_Float16*)(ws);              // 8 MB   [8192][512] f16
    _Float16* wqkvb = (_Float16*)(ws + 8388608);    // 1.5 MB [1536][512]
    _Float16* wob   = (_Float16*)(ws + 9961472);    // 0.5 MB [512][512]
    _Float16* Qb    = (_Float16*)(ws + 10485760);   // 8 MB   [b,h,n,d] (pre-scaled)
    _Float16* Kb    = (_Float16*)(ws + 18874368);   // 8 MB   [b,h,n,d]
    _Float16* VTb   = (_Float16*)(ws + 27262976);   // 8 MB   [b,h,d,n]
    _Float16* attnb = (_Float16*)(ws);              // alias xb (x dead after proj)

    convert_k<<<5120, 256, 0, stream>>>(x, wq, wk, wv, wo, xb, wqkvb, wob);
    qkv_proj<<<dim3(12, 64), 256, 0, stream>>>(xb, wqkvb, Qb, Kb, VTb);
    attn_k<<<dim3(8, 64), 256, 0, stream>>>(Qb, Kb, VTb, attnb);
    out_proj<<<dim3(4, 64), 256, 0, stream>>>(attnb, wob, bo, out);
}

// Round 2
// 168.939 us; speedup vs baseline: 1.0964x; 1.0964x over previous
//
#include <hip/hip_runtime.h>
#include <hip/hip_fp16.h>

#define BATCH 8
#define SEQ   1024
#define DIM   512
#define HEADS 8
#define DHEAD 64
#define MTOT  (BATCH*SEQ)   // 8192

typedef _Float16 f16x8 __attribute__((ext_vector_type(8)));
typedef _Float16 f16x4 __attribute__((ext_vector_type(4)));
typedef float    fx4   __attribute__((ext_vector_type(4)));

#define MFMA16 __builtin_amdgcn_mfma_f32_16x16x32_f16

// ---------------------------------------------------------------------------
// Kernel 0: fp32 -> fp16 conversion (x, wq|wk|wv concat, wo)
// ---------------------------------------------------------------------------
__global__ __launch_bounds__(256) void convert_k(
    const float* __restrict__ x,  const float* __restrict__ wq,
    const float* __restrict__ wk, const float* __restrict__ wv,
    const float* __restrict__ wo,
    _Float16* __restrict__ xb, _Float16* __restrict__ wqkvb,
    _Float16* __restrict__ wob)
{
    const int XU = (MTOT*DIM)/4;   // 1048576 float4 units
    const int WU = (DIM*DIM)/4;    // 65536 units per weight
    int idx = blockIdx.x*256 + threadIdx.x;
    if (idx >= XU + 4*WU) return;
    const float* src; _Float16* dst;
    if (idx < XU) { src = x + idx*4; dst = xb + idx*4; }
    else {
        int t = idx - XU; int region = t >> 16; int off = (t & 65535)*4;
        if      (region == 0) { src = wq + off; dst = wqkvb + off; }
        else if (region == 1) { src = wk + off; dst = wqkvb + DIM*DIM + off; }
        else if (region == 2) { src = wv + off; dst = wqkvb + 2*DIM*DIM + off; }
        else                  { src = wo + off; dst = wob + off; }
    }
    float4 v = *(const float4*)src;
    f16x4 o = { (_Float16)v.x, (_Float16)v.y, (_Float16)v.z, (_Float16)v.w };
    *(f16x4*)dst = o;
}

// ---------------------------------------------------------------------------
// Kernel 1: fused QKV projection GEMM  (M=8192, N=1536, K=512), A@B^T
// Epilogue: Q scaled by 0.125 -> [b,h,n,d]; K -> [b,h,n,d]; V -> [b,h,d,n]
// V stores pack the 4 consecutive seq positions per lane into one 8B store.
// ---------------------------------------------------------------------------
__global__ __launch_bounds__(256,2) void qkv_proj(
    const _Float16* __restrict__ A, const _Float16* __restrict__ B,
    _Float16* __restrict__ Qb, _Float16* __restrict__ Kb,
    _Float16* __restrict__ VTb)
{
    __shared__ _Float16 lA[128*72];
    __shared__ _Float16 lB[128*72];
    const int tid = threadIdx.x;
    const int m0 = blockIdx.y*128, n0 = blockIdx.x*128;
    const int w = tid>>6, l = tid&63, lr = l&15, lq = l>>4;
    const int wr = w>>1, wc = w&1;
    fx4 acc[4][4] = {};

    for (int k0 = 0; k0 < DIM; k0 += 64) {
        __syncthreads();
#pragma unroll
        for (int i = 0; i < 4; i++) {
            int u = tid + i*256;            // 1024 16B-units per tile
            int row = u >> 3, cu = (u & 7)*8;
            *(f16x8*)&lA[row*72 + cu] = *(const f16x8*)&A[(m0+row)*DIM + k0 + cu];
            *(f16x8*)&lB[row*72 + cu] = *(const f16x8*)&B[(n0+row)*DIM + k0 + cu];
        }
        __syncthreads();
#pragma unroll
        for (int kb = 0; kb < 2; kb++) {
            f16x8 af[4], bf[4];
#pragma unroll
            for (int cb = 0; cb < 4; cb++)
                bf[cb] = *(const f16x8*)&lB[(wc*64+cb*16+lr)*72 + kb*32 + lq*8];
#pragma unroll
            for (int rb = 0; rb < 4; rb++)
                af[rb] = *(const f16x8*)&lA[(wr*64+rb*16+lr)*72 + kb*32 + lq*8];
#pragma unroll
            for (int rb = 0; rb < 4; rb++)
#pragma unroll
                for (int cb = 0; cb < 4; cb++)
                    acc[rb][cb] = MFMA16(af[rb], bf[cb], acc[rb][cb], 0,0,0);
        }
    }
    if (n0 >= 1024) {
        // ---- V region: V^T layout [b,h,d,n]; 4 acc rows = 4 consecutive n ----
#pragma unroll
        for (int rb = 0; rb < 4; rb++)
#pragma unroll
            for (int cb = 0; cb < 4; cb++) {
                int inner = (n0 - 1024) + wc*64 + cb*16 + lr;
                int h = inner >> 6, d = inner & 63;
                int m = m0 + wr*64 + rb*16 + lq*4;
                int b = m >> 10, n = m & 1023;
                f16x4 v4;
#pragma unroll
                for (int i = 0; i < 4; i++) v4[i] = (_Float16)acc[rb][cb][i];
                *(f16x4*)&VTb[((size_t)(b*HEADS+h)*DHEAD + d)*SEQ + n] = v4;
            }
    } else {
        // ---- Q/K regions ----
#pragma unroll
        for (int rb = 0; rb < 4; rb++)
#pragma unroll
            for (int cb = 0; cb < 4; cb++) {
                int nn = n0 + wc*64 + cb*16 + lr;
                int which = nn >> 9, inner = nn & 511, h = inner >> 6, d = inner & 63;
#pragma unroll
                for (int i = 0; i < 4; i++) {
                    int m = m0 + wr*64 + rb*16 + lq*4 + i;
                    int b = m >> 10, n = m & 1023;
                    float v = acc[rb][cb][i];
                    if (which == 0)
                        Qb[((b*HEADS+h)*SEQ + n)*DHEAD + d] = (_Float16)(v * 0.125f);
                    else
                        Kb[((b*HEADS+h)*SEQ + n)*DHEAD + d] = (_Float16)v;
                }
            }
    }
}

// ---------------------------------------------------------------------------
// Kernel 2: attention per (b,h). 512 threads = 8 waves x 16 Q-rows.
// S = Q·K^T (scale folded into Q); P = exp(clip(S,1e-6,1)); O = P·V / rowsum.
// P tile in LDS is XOR-swizzled (16B chunks by row>>2) -> 2-way banks (free).
// ---------------------------------------------------------------------------
__global__ __launch_bounds__(512,4) void attn_k(
    const _Float16* __restrict__ Q, const _Float16* __restrict__ K,
    const _Float16* __restrict__ VT, _Float16* __restrict__ AO)
{
    __shared__ _Float16 lKV[128*72];        // K tile [128][72] / VT tile [64][136]
    __shared__ _Float16 lP[8][16*136];      // per-wave P tile [16][136], swizzled
    const int tid = threadIdx.x;
    const int w = tid>>6, l = tid&63, lr = l&15, lq = l>>4;
    const int bh = blockIdx.y, q0 = blockIdx.x*128;
    const int b = bh>>3, h = bh&7;
    const _Float16* Qp = Q  + (size_t)bh*SEQ*DHEAD;
    const _Float16* Kp = K  + (size_t)bh*SEQ*DHEAD;
    const _Float16* Vp = VT + (size_t)bh*DHEAD*SEQ;

    f16x8 qf[2];
#pragma unroll
    for (int kb = 0; kb < 2; kb++)
        qf[kb] = *(const f16x8*)&Qp[(q0 + w*16 + lr)*DHEAD + kb*32 + lq*8];

    fx4 O[4] = {};
    fx4 lsum = {};

    for (int kt = 0; kt < 8; kt++) {
        int k0 = kt*128;
        __syncthreads();
#pragma unroll
        for (int i = 0; i < 2; i++) {        // stage K tile [128][64]
            int u = tid + i*512;
            int row = u >> 3, cu = (u & 7)*8;
            *(f16x8*)&lKV[row*72 + cu] = *(const f16x8*)&Kp[(k0+row)*DHEAD + cu];
        }
        __syncthreads();
        // ---- S = Q K^T, clip, exp, write P to LDS (swizzled), rowsum ----
#pragma unroll
        for (int cb = 0; cb < 8; cb++) {
            f16x8 kf[2];
#pragma unroll
            for (int kb = 0; kb < 2; kb++)
                kf[kb] = *(const f16x8*)&lKV[(cb*16+lr)*72 + kb*32 + lq*8];
            fx4 s = {};
            s = MFMA16(qf[0], kf[0], s, 0,0,0);
            s = MFMA16(qf[1], kf[1], s, 0,0,0);
            // P[r=lq*4+i][c=cb*16+lr] stored at r*136 + ((c>>3)^( (r>>2)<<1 ))*8 + (c&7)
            int pbase = (lq*4)*136 + (((cb*2 + (lr>>3)) ^ (lq<<1))*8) + (lr&7);
#pragma unroll
            for (int i = 0; i < 4; i++) {
                float p = __expf(__builtin_amdgcn_fmed3f(s[i], 1e-6f, 1.0f));
                lsum[i] += p;
                lP[w][pbase + i*136] = (_Float16)p;
            }
        }
        __syncthreads();
#pragma unroll
        for (int i = 0; i < 2; i++) {        // stage V^T tile [64][128]
            int u = tid + i*512;
            int row = u >> 4, cu = (u & 15)*8;
            *(f16x8*)&lKV[row*136 + cu] = *(const f16x8*)&Vp[row*SEQ + k0 + cu];
        }
        __syncthreads();
        // ---- O += P V ----
#pragma unroll
        for (int ks = 0; ks < 4; ks++) {
            f16x8 af = *(const f16x8*)
                &lP[w][lr*136 + (((ks*4 + lq) ^ (((lr>>2)&3)<<1))*8)];
#pragma unroll
            for (int db = 0; db < 4; db++) {
                f16x8 vf = *(const f16x8*)&lKV[(db*16+lr)*136 + ks*32 + lq*8];
                O[db] = MFMA16(af, vf, O[db], 0,0,0);
            }
        }
    }
    // rowsum reduction across the 16 col-lanes
#pragma unroll
    for (int i = 0; i < 4; i++) {
        float s = lsum[i];
        s += __shfl_xor(s, 1);
        s += __shfl_xor(s, 2);
        s += __shfl_xor(s, 4);
        s += __shfl_xor(s, 8);
        lsum[i] = s;
    }
    fx4 inv;
#pragma unroll
    for (int i = 0; i < 4; i++) inv[i] = 1.0f / lsum[i];
#pragma unroll
    for (int db = 0; db < 4; db++)
#pragma unroll
        for (int i = 0; i < 4; i++) {
            int n = q0 + w*16 + lq*4 + i;
            int d = db*16 + lr;
            AO[((size_t)(b*SEQ + n)*HEADS + h)*DHEAD + d] =
                (_Float16)(O[db][i] * inv[i]);
        }
}

// ---------------------------------------------------------------------------
// Kernel 3: output projection  out = AO @ wo^T + bo   (M=8192, N=512, K=512)
// ---------------------------------------------------------------------------
__global__ __launch_bounds__(256,2) void out_proj(
    const _Float16* __restrict__ A, const _Float16* __restrict__ B,
    const float* __restrict__ bo, float* __restrict__ out)
{
    __shared__ _Float16 lA[128*72];
    __shared__ _Float16 lB[128*72];
    const int tid = threadIdx.x;
    const int m0 = blockIdx.y*128, n0 = blockIdx.x*128;
    const int w = tid>>6, l = tid&63, lr = l&15, lq = l>>4;
    const int wr = w>>1, wc = w&1;
    fx4 acc[4][4] = {};

    for (int k0 = 0; k0 < DIM; k0 += 64) {
        __syncthreads();
#pragma unroll
        for (int i = 0; i < 4; i++) {
            int u = tid + i*256;
            int row = u >> 3, cu = (u & 7)*8;
            *(f16x8*)&lA[row*72 + cu] = *(const f16x8*)&A[(m0+row)*DIM + k0 + cu];
            *(f16x8*)&lB[row*72 + cu] = *(const f16x8*)&B[(n0+row)*DIM + k0 + cu];
        }
        __syncthreads();
#pragma unroll
        for (int kb = 0; kb < 2; kb++) {
            f16x8 af[4], bf[4];
#pragma unroll
            for (int cb = 0; cb < 4; cb++)
                bf[cb] = *(const f16x8*)&lB[(wc*64+cb*16+lr)*72 + kb*32 + lq*8];
#pragma unroll
            for (int rb = 0; rb < 4; rb++)
                af[rb] = *(const f16x8*)&lA[(wr*64+rb*16+lr)*72 + kb*32 + lq*8];
#pragma unroll
            for (int rb = 0; rb < 4; rb++)
#pragma unroll
                for (int cb = 0; cb < 4; cb++)
                    acc[rb][cb] = MFMA16(af[rb], bf[cb], acc[rb][cb], 0,0,0);
        }
    }
#pragma unroll
    for (int rb = 0; rb < 4; rb++)
#pragma unroll
        for (int cb = 0; cb < 4; cb++) {
            int nn = n0 + wc*64 + cb*16 + lr;
            float bias = bo[nn];
#pragma unroll
            for (int i = 0; i < 4; i++) {
                int m = m0 + wr*64 + rb*16 + lq*4 + i;
                out[(size_t)m*DIM + nn] = acc[rb][cb][i] + bias;
            }
        }
}

// ---------------------------------------------------------------------------
extern "C" void kernel_launch(void* const* d_in, const int* in_sizes, int n_in,
                              void* d_out, int out_size, void* d_ws, size_t ws_size,
                              hipStream_t stream)
{
    const float* x  = (const float*)d_in[0];
    const float* wq = (const float*)d_in[1];
    const float* wk = (const float*)d_in[2];
    const float* wv = (const float*)d_in[3];
    const float* wo = (const float*)d_in[4];
    const float* bo = (const float*)d_in[5];
    float* out = (float*)d_out;
    char* ws = (char*)d_ws;

    // workspace layout (bytes):
    _Float16* xb    = (_Float16*)(ws);              // 8 MB   [8192][512] f16
    _Float16* wqkvb = (_Float16*)(ws + 8388608);    // 1.5 MB [1536][512]
    _Float16* wob   = (_Float16*)(ws + 9961472);    // 0.5 MB [512][512]
    _Float16* Qb    = (_Float16*)(ws + 10485760);   // 8 MB   [b,h,n,d] (pre-scaled)
    _Float16* Kb    = (_Float16*)(ws + 18874368);   // 8 MB   [b,h,n,d]
    _Float16* VTb   = (_Float16*)(ws + 27262976);   // 8 MB   [b,h,d,n]
    _Float16* attnb = (_Float16*)(ws);              // alias xb (x dead after proj)

    convert_k<<<5120, 256, 0, stream>>>(x, wq, wk, wv, wo, xb, wqkvb, wob);
    qkv_proj<<<dim3(12, 64), 256, 0, stream>>>(xb, wqkvb, Qb, Kb, VTb);
    attn_k<<<dim3(8, 64), 512, 0, stream>>>(Qb, Kb, VTb, attnb);
    out_proj<<<dim3(4, 64), 256, 0, stream>>>(attnb, wob, bo, out);
}

// Round 3
// 157.727 us; speedup vs baseline: 1.1743x; 1.0711x over previous
//
#include <hip/hip_runtime.h>
#include <hip/hip_fp16.h>

#define BATCH 8
#define SEQ   1024
#define DIM   512
#define HEADS 8
#define DHEAD 64
#define MTOT  (BATCH*SEQ)   // 8192

typedef _Float16 f16x8 __attribute__((ext_vector_type(8)));
typedef _Float16 f16x4 __attribute__((ext_vector_type(4)));
typedef float    fx4   __attribute__((ext_vector_type(4)));

#define MFMA16 __builtin_amdgcn_mfma_f32_16x16x32_f16

// async global->LDS, 16B per lane; LDS dest = wave-uniform base + lane*16
__device__ __forceinline__ void gload16(const _Float16* g, _Float16* l) {
    __builtin_amdgcn_global_load_lds(
        (const __attribute__((address_space(1))) unsigned int*)g,
        (__attribute__((address_space(3))) unsigned int*)l, 16, 0, 0);
}

// ---------------------------------------------------------------------------
// Kernel 0: fp32 -> fp16 conversion (x, wq|wk|wv concat, wo)
// ---------------------------------------------------------------------------
__global__ __launch_bounds__(256) void convert_k(
    const float* __restrict__ x,  const float* __restrict__ wq,
    const float* __restrict__ wk, const float* __restrict__ wv,
    const float* __restrict__ wo,
    _Float16* __restrict__ xb, _Float16* __restrict__ wqkvb,
    _Float16* __restrict__ wob)
{
    const int XU = (MTOT*DIM)/4;   // 1048576 float4 units
    const int WU = (DIM*DIM)/4;    // 65536 units per weight
    int idx = blockIdx.x*256 + threadIdx.x;
    if (idx >= XU + 4*WU) return;
    const float* src; _Float16* dst;
    if (idx < XU) { src = x + idx*4; dst = xb + idx*4; }
    else {
        int t = idx - XU; int region = t >> 16; int off = (t & 65535)*4;
        if      (region == 0) { src = wq + off; dst = wqkvb + off; }
        else if (region == 1) { src = wk + off; dst = wqkvb + DIM*DIM + off; }
        else if (region == 2) { src = wv + off; dst = wqkvb + 2*DIM*DIM + off; }
        else                  { src = wo + off; dst = wob + off; }
    }
    float4 v = *(const float4*)src;
    f16x4 o = { (_Float16)v.x, (_Float16)v.y, (_Float16)v.z, (_Float16)v.w };
    *(f16x4*)dst = o;
}

// ---------------------------------------------------------------------------
// Kernel 1: fused QKV projection GEMM  (M=8192, N=1536, K=512), A@B^T
// m97-style: global_load_lds width-16 staging into unpadded [128][64] tiles.
// Epilogue: Q scaled by 0.125 -> [b,h,n,d]; K -> [b,h,n,d]; V -> [b,h,d,n]
// ---------------------------------------------------------------------------
__global__ __launch_bounds__(256,3) void qkv_proj(
    const _Float16* __restrict__ A, const _Float16* __restrict__ B,
    _Float16* __restrict__ Qb, _Float16* __restrict__ Kb,
    _Float16* __restrict__ VTb)
{
    __shared__ _Float16 lA[128*64];
    __shared__ _Float16 lB[128*64];
    const int tid = threadIdx.x;
    const int m0 = blockIdx.y*128, n0 = blockIdx.x*128;
    const int w = tid>>6, l = tid&63, lr = l&15, lq = l>>4;
    const int wr = w>>1, wc = w&1;
    const int srow = (l>>3), scol = (l&7)*8;   // staging lane map
    fx4 acc[4][4] = {};

    for (int k0 = 0; k0 < DIM; k0 += 64) {
        __syncthreads();
#pragma unroll
        for (int t = 0; t < 4; t++) {          // wave w stages rows w*32..+31
            int row = w*32 + t*8;
            gload16(&A[(size_t)(m0+row+srow)*DIM + k0 + scol], &lA[row*64]);
            gload16(&B[(size_t)(n0+row+srow)*DIM + k0 + scol], &lB[row*64]);
        }
        __syncthreads();
#pragma unroll
        for (int kb = 0; kb < 2; kb++) {
            f16x8 af[4], bf[4];
#pragma unroll
            for (int cb = 0; cb < 4; cb++)
                bf[cb] = *(const f16x8*)&lB[(wc*64+cb*16+lr)*64 + kb*32 + lq*8];
#pragma unroll
            for (int rb = 0; rb < 4; rb++)
                af[rb] = *(const f16x8*)&lA[(wr*64+rb*16+lr)*64 + kb*32 + lq*8];
#pragma unroll
            for (int rb = 0; rb < 4; rb++)
#pragma unroll
                for (int cb = 0; cb < 4; cb++)
                    acc[rb][cb] = MFMA16(af[rb], bf[cb], acc[rb][cb], 0,0,0);
        }
    }
    if (n0 >= 1024) {
        // ---- V region: V^T layout [b,h,d,n]; 4 acc rows = 4 consecutive n ----
#pragma unroll
        for (int rb = 0; rb < 4; rb++)
#pragma unroll
            for (int cb = 0; cb < 4; cb++) {
                int inner = (n0 - 1024) + wc*64 + cb*16 + lr;
                int h = inner >> 6, d = inner & 63;
                int m = m0 + wr*64 + rb*16 + lq*4;
                int b = m >> 10, n = m & 1023;
                f16x4 v4;
#pragma unroll
                for (int i = 0; i < 4; i++) v4[i] = (_Float16)acc[rb][cb][i];
                *(f16x4*)&VTb[((size_t)(b*HEADS+h)*DHEAD + d)*SEQ + n] = v4;
            }
    } else {
        // ---- Q/K regions ----
#pragma unroll
        for (int rb = 0; rb < 4; rb++)
#pragma unroll
            for (int cb = 0; cb < 4; cb++) {
                int nn = n0 + wc*64 + cb*16 + lr;
                int which = nn >> 9, inner = nn & 511, h = inner >> 6, d = inner & 63;
#pragma unroll
                for (int i = 0; i < 4; i++) {
                    int m = m0 + wr*64 + rb*16 + lq*4 + i;
                    int b = m >> 10, n = m & 1023;
                    float v = acc[rb][cb][i];
                    if (which == 0)
                        Qb[((b*HEADS+h)*SEQ + n)*DHEAD + d] = (_Float16)(v * 0.125f);
                    else
                        Kb[((b*HEADS+h)*SEQ + n)*DHEAD + d] = (_Float16)v;
                }
            }
    }
}

// ---------------------------------------------------------------------------
// Kernel 2: attention per (b,h), S-TRANSPOSED formulation.
// 256 threads = 4 waves x 16 Q-rows (q-tile 64). K/V tiles of 128.
//   S^T = K.Q^T  (C-layout: row=j, col=q)  -> lane holds 4 consecutive j
//   P^T packed b64 into tiny per-wave LDS slice, consumed per-ks by
//   O^T = VT.P   (A=VT d-major, B=P^T read b128)
// 2 barriers per kt; O^T lanes hold 4 consecutive d -> packed b64 stores.
// ---------------------------------------------------------------------------
__global__ __launch_bounds__(256,4) void attn_k(
    const _Float16* __restrict__ Q, const _Float16* __restrict__ K,
    const _Float16* __restrict__ VT, _Float16* __restrict__ AO)
{
    __shared__ _Float16 lK[128*64];      // unpadded (global_load_lds)
    __shared__ _Float16 lVT[64*136];     // padded, VGPR-staged
    __shared__ _Float16 lPT[4][16*48];   // per-wave P^T slice [q=16][j=32 +pad]
    const int tid = threadIdx.x;
    const int w = tid>>6, l = tid&63, lr = l&15, lq = l>>4;
    const int bh = blockIdx.y, q0 = blockIdx.x*64;
    const int b = bh>>3, h = bh&7;
    const _Float16* Qp = Q  + (size_t)bh*SEQ*DHEAD;
    const _Float16* Kp = K  + (size_t)bh*SEQ*DHEAD;
    const _Float16* Vp = VT + (size_t)bh*DHEAD*SEQ;
    const int srow = (l>>3), scol = (l&7)*8;

    // Q as B-operand fragment (n=q=lr, k=d): same read as before
    f16x8 qf[2];
#pragma unroll
    for (int kb = 0; kb < 2; kb++)
        qf[kb] = *(const f16x8*)&Qp[(q0 + w*16 + lr)*DHEAD + kb*32 + lq*8];

    fx4 O[4] = {};           // O^T: 4 d-blocks x (4 d per lane)
    float lsum = 0.0f;       // per-lane partial rowsum for q=lr

    for (int kt = 0; kt < 8; kt++) {
        int k0 = kt*128;
        __syncthreads();
#pragma unroll
        for (int t = 0; t < 4; t++) {       // K tile [128][64] via glds
            int row = w*32 + t*8;
            gload16(&Kp[(size_t)(k0+row+srow)*DHEAD + scol], &lK[row*64]);
        }
#pragma unroll
        for (int i = 0; i < 4; i++) {       // VT tile [64][128] -> [64][136]
            int u = tid + i*256;
            int row = u >> 4, cu = (u & 15)*8;
            *(f16x8*)&lVT[row*136 + cu] = *(const f16x8*)&Vp[(size_t)row*SEQ + k0 + cu];
        }
        __syncthreads();

#pragma unroll
        for (int ks = 0; ks < 4; ks++) {
            // produce P^T for j-slice [ks*32, ks*32+32)
#pragma unroll
            for (int half = 0; half < 2; half++) {
                int rb = ks*2 + half;
                f16x8 kf0 = *(const f16x8*)&lK[(rb*16+lr)*64 + lq*8];
                f16x8 kf1 = *(const f16x8*)&lK[(rb*16+lr)*64 + 32 + lq*8];
                fx4 s = {};
                s = MFMA16(kf0, qf[0], s, 0,0,0);
                s = MFMA16(kf1, qf[1], s, 0,0,0);
                f16x4 p4;
#pragma unroll
                for (int i = 0; i < 4; i++) {
                    float p = __expf(__builtin_amdgcn_fmed3f(s[i], 1e-6f, 1.0f));
                    lsum += p;
                    p4[i] = (_Float16)p;
                }
                // P^T[j=rb*16+lq*4+i][q=lr] -> packed along j
                *(f16x4*)&lPT[w][lr*48 + half*16 + lq*4] = p4;
            }
            // consume: O^T += VT . P^T-slice
            f16x8 pf = *(const f16x8*)&lPT[w][lr*48 + lq*8];
#pragma unroll
            for (int db = 0; db < 4; db++) {
                f16x8 vf = *(const f16x8*)&lVT[(db*16+lr)*136 + ks*32 + lq*8];
                O[db] = MFMA16(vf, pf, O[db], 0,0,0);
            }
        }
    }
    // rowsum for q=lr: reduce across the 4 quads
    lsum += __shfl_xor(lsum, 16);
    lsum += __shfl_xor(lsum, 32);
    float inv = 1.0f / lsum;

    const int n = q0 + w*16 + lr;
    _Float16* aop = AO + ((size_t)(b*SEQ + n)*HEADS + h)*DHEAD;
#pragma unroll
    for (int db = 0; db < 4; db++) {
        f16x4 o4;
#pragma unroll
        for (int i = 0; i < 4; i++) o4[i] = (_Float16)(O[db][i] * inv);
        *(f16x4*)&aop[db*16 + lq*4] = o4;
    }
}

// ---------------------------------------------------------------------------
// Kernel 3: output projection  out = AO @ wo^T + bo   (M=8192, N=512, K=512)
// ---------------------------------------------------------------------------
__global__ __launch_bounds__(256,3) void out_proj(
    const _Float16* __restrict__ A, const _Float16* __restrict__ B,
    const float* __restrict__ bo, float* __restrict__ out)
{
    __shared__ _Float16 lA[128*64];
    __shared__ _Float16 lB[128*64];
    const int tid = threadIdx.x;
    const int m0 = blockIdx.y*128, n0 = blockIdx.x*128;
    const int w = tid>>6, l = tid&63, lr = l&15, lq = l>>4;
    const int wr = w>>1, wc = w&1;
    const int srow = (l>>3), scol = (l&7)*8;
    fx4 acc[4][4] = {};

    for (int k0 = 0; k0 < DIM; k0 += 64) {
        __syncthreads();
#pragma unroll
        for (int t = 0; t < 4; t++) {
            int row = w*32 + t*8;
            gload16(&A[(size_t)(m0+row+srow)*DIM + k0 + scol], &lA[row*64]);
            gload16(&B[(size_t)(n0+row+srow)*DIM + k0 + scol], &lB[row*64]);
        }
        __syncthreads();
#pragma unroll
        for (int kb = 0; kb < 2; kb++) {
            f16x8 af[4], bf[4];
#pragma unroll
            for (int cb = 0; cb < 4; cb++)
                bf[cb] = *(const f16x8*)&lB[(wc*64+cb*16+lr)*64 + kb*32 + lq*8];
#pragma unroll
            for (int rb = 0; rb < 4; rb++)
                af[rb] = *(const f16x8*)&lA[(wr*64+rb*16+lr)*64 + kb*32 + lq*8];
#pragma unroll
            for (int rb = 0; rb < 4; rb++)
#pragma unroll
                for (int cb = 0; cb < 4; cb++)
                    acc[rb][cb] = MFMA16(af[rb], bf[cb], acc[rb][cb], 0,0,0);
        }
    }
#pragma unroll
    for (int rb = 0; rb < 4; rb++)
#pragma unroll
        for (int cb = 0; cb < 4; cb++) {
            int nn = n0 + wc*64 + cb*16 + lr;
            float bias = bo[nn];
#pragma unroll
            for (int i = 0; i < 4; i++) {
                int m = m0 + wr*64 + rb*16 + lq*4 + i;
                out[(size_t)m*DIM + nn] = acc[rb][cb][i] + bias;
            }
        }
}

// ---------------------------------------------------------------------------
extern "C" void kernel_launch(void* const* d_in, const int* in_sizes, int n_in,
                              void* d_out, int out_size, void* d_ws, size_t ws_size,
                              hipStream_t stream)
{
    const float* x  = (const float*)d_in[0];
    const float* wq = (const float*)d_in[1];
    const float* wk = (const float*)d_in[2];
    const float* wv = (const float*)d_in[3];
    const float* wo = (const float*)d_in[4];
    const float* bo = (const float*)d_in[5];
    float* out = (float*)d_out;
    char* ws = (char*)d_ws;

    // workspace layout (bytes):
    _Float16* xb    = (_Float16*)(ws);              // 8 MB   [8192][512] f16
    _Float16* wqkvb = (_Float16*)(ws + 8388608);    // 1.5 MB [1536][512]
    _Float16* wob   = (_Float16*)(ws + 9961472);    // 0.5 MB [512][512]
    _Float16* Qb    = (_Float16*)(ws + 10485760);   // 8 MB   [b,h,n,d] (pre-scaled)
    _Float16* Kb    = (_Float16*)(ws + 18874368);   // 8 MB   [b,h,n,d]
    _Float16* VTb   = (_Float16*)(ws + 27262976);   // 8 MB   [b,h,d,n]
    _Float16* attnb = (_Float16*)(ws);              // alias xb (x dead after proj)

    convert_k<<<5120, 256, 0, stream>>>(x, wq, wk, wv, wo, xb, wqkvb, wob);
    qkv_proj<<<dim3(12, 64), 256, 0, stream>>>(xb, wqkvb, Qb, Kb, VTb);
    attn_k<<<dim3(16, 64), 256, 0, stream>>>(Qb, Kb, VTb, attnb);
    out_proj<<<dim3(4, 64), 256, 0, stream>>>(attnb, wob, bo, out);
}

// Round 4
// 152.996 us; speedup vs baseline: 1.2106x; 1.0309x over previous
//
#include <hip/hip_runtime.h>
#include <hip/hip_fp16.h>

#define BATCH 8
#define SEQ   1024
#define DIM   512
#define HEADS 8
#define DHEAD 64
#define MTOT  (BATCH*SEQ)   // 8192

typedef _Float16 f16x8 __attribute__((ext_vector_type(8)));
typedef _Float16 f16x4 __attribute__((ext_vector_type(4)));
typedef float    fx4   __attribute__((ext_vector_type(4)));

#define MFMA16 __builtin_amdgcn_mfma_f32_16x16x32_f16

// async global->LDS, 16B per lane; LDS dest = wave-uniform base + lane*16
__device__ __forceinline__ void gload16(const _Float16* g, _Float16* l) {
    __builtin_amdgcn_global_load_lds(
        (const __attribute__((address_space(1))) unsigned int*)g,
        (__attribute__((address_space(3))) unsigned int*)l, 16, 0, 0);
}

// ---------------------------------------------------------------------------
// Kernel 0: fp32 -> fp16 conversion (x, wq|wk|wv concat, wo)
// ---------------------------------------------------------------------------
__global__ __launch_bounds__(256) void convert_k(
    const float* __restrict__ x,  const float* __restrict__ wq,
    const float* __restrict__ wk, const float* __restrict__ wv,
    const float* __restrict__ wo,
    _Float16* __restrict__ xb, _Float16* __restrict__ wqkvb,
    _Float16* __restrict__ wob)
{
    const int XU = (MTOT*DIM)/4;   // 1048576 float4 units
    const int WU = (DIM*DIM)/4;    // 65536 units per weight
    int idx = blockIdx.x*256 + threadIdx.x;
    if (idx >= XU + 4*WU) return;
    const float* src; _Float16* dst;
    if (idx < XU) { src = x + idx*4; dst = xb + idx*4; }
    else {
        int t = idx - XU; int region = t >> 16; int off = (t & 65535)*4;
        if      (region == 0) { src = wq + off; dst = wqkvb + off; }
        else if (region == 1) { src = wk + off; dst = wqkvb + DIM*DIM + off; }
        else if (region == 2) { src = wv + off; dst = wqkvb + 2*DIM*DIM + off; }
        else                  { src = wo + off; dst = wob + off; }
    }
    float4 v = *(const float4*)src;
    f16x4 o = { (_Float16)v.x, (_Float16)v.y, (_Float16)v.z, (_Float16)v.w };
    *(f16x4*)dst = o;
}

// ---------------------------------------------------------------------------
// Kernel 1: fused QKV projection GEMM  (M=8192, N=1536, K=512), A@B^T
// glds staging with XOR chunk-swizzle (slot = chunk ^ (row&7)) -> 2-way banks.
// ---------------------------------------------------------------------------
__global__ __launch_bounds__(256,3) void qkv_proj(
    const _Float16* __restrict__ A, const _Float16* __restrict__ B,
    _Float16* __restrict__ Qb, _Float16* __restrict__ Kb,
    _Float16* __restrict__ VTb)
{
    __shared__ _Float16 lA[128*64];
    __shared__ _Float16 lB[128*64];
    const int tid = threadIdx.x;
    const int m0 = blockIdx.y*128, n0 = blockIdx.x*128;
    const int w = tid>>6, l = tid&63, lr = l&15, lq = l>>4;
    const int wr = w>>1, wc = w&1;
    const int srow = (l>>3);
    const int scol = ((l&7) ^ ((l>>3)&7))*8;   // swizzled global chunk
    const int sw = lr&7;
    fx4 acc[4][4] = {};

    for (int k0 = 0; k0 < DIM; k0 += 64) {
        __syncthreads();
#pragma unroll
        for (int t = 0; t < 4; t++) {          // wave w stages rows w*32..+31
            int row = w*32 + t*8;
            gload16(&A[(size_t)(m0+row+srow)*DIM + k0 + scol], &lA[row*64]);
            gload16(&B[(size_t)(n0+row+srow)*DIM + k0 + scol], &lB[row*64]);
        }
        __syncthreads();
#pragma unroll
        for (int kb = 0; kb < 2; kb++) {
            f16x8 af[4], bf[4];
#pragma unroll
            for (int cb = 0; cb < 4; cb++)
                bf[cb] = *(const f16x8*)&lB[(wc*64+cb*16+lr)*64 + (((kb*4+lq)^sw))*8];
#pragma unroll
            for (int rb = 0; rb < 4; rb++)
                af[rb] = *(const f16x8*)&lA[(wr*64+rb*16+lr)*64 + (((kb*4+lq)^sw))*8];
#pragma unroll
            for (int rb = 0; rb < 4; rb++)
#pragma unroll
                for (int cb = 0; cb < 4; cb++)
                    acc[rb][cb] = MFMA16(af[rb], bf[cb], acc[rb][cb], 0,0,0);
        }
    }
    if (n0 >= 1024) {
        // ---- V region: V^T layout [b,h,d,n]; 4 acc rows = 4 consecutive n ----
#pragma unroll
        for (int rb = 0; rb < 4; rb++)
#pragma unroll
            for (int cb = 0; cb < 4; cb++) {
                int inner = (n0 - 1024) + wc*64 + cb*16 + lr;
                int h = inner >> 6, d = inner & 63;
                int m = m0 + wr*64 + rb*16 + lq*4;
                int b = m >> 10, n = m & 1023;
                f16x4 v4;
#pragma unroll
                for (int i = 0; i < 4; i++) v4[i] = (_Float16)acc[rb][cb][i];
                *(f16x4*)&VTb[((size_t)(b*HEADS+h)*DHEAD + d)*SEQ + n] = v4;
            }
    } else {
        // ---- Q/K regions ----
#pragma unroll
        for (int rb = 0; rb < 4; rb++)
#pragma unroll
            for (int cb = 0; cb < 4; cb++) {
                int nn = n0 + wc*64 + cb*16 + lr;
                int which = nn >> 9, inner = nn & 511, h = inner >> 6, d = inner & 63;
#pragma unroll
                for (int i = 0; i < 4; i++) {
                    int m = m0 + wr*64 + rb*16 + lq*4 + i;
                    int b = m >> 10, n = m & 1023;
                    float v = acc[rb][cb][i];
                    if (which == 0)
                        Qb[((b*HEADS+h)*SEQ + n)*DHEAD + d] = (_Float16)(v * 0.125f);
                    else
                        Kb[((b*HEADS+h)*SEQ + n)*DHEAD + d] = (_Float16)v;
                }
            }
    }
}

// ---------------------------------------------------------------------------
// Kernel 2: attention per (b,h), S-transposed + J-SPLIT across waves.
// Block = 256 thr = 4 waves, q-tile 64. Wave w owns j-slice [w*32, w*32+32).
//   S^T = K_slice.Q^T ; P^T (q-major) in per-wave LDS ; O^T += VT_slice.P
// Per wave per kt: 4 kf + 4 vf + 4 pf b128 reads (vs 36 in v2), 8 b64 writes.
// End: cross-wave O (f16 partials) + rowsum reduction via LDS, wave 0 stores.
// All tiles glds-staged with XOR chunk-swizzle -> <=2-way banks everywhere.
// ---------------------------------------------------------------------------
__global__ __launch_bounds__(256,3) void attn_k(
    const _Float16* __restrict__ Q, const _Float16* __restrict__ K,
    const _Float16* __restrict__ VT, _Float16* __restrict__ AO)
{
    __shared__ __align__(16) char smem[53248];
    _Float16* lK  = (_Float16*)smem;            // [128][64], chunk-swizzled
    _Float16* lVT = (_Float16*)(smem + 16384);  // [64][128], chunk-swizzled
    _Float16* lPT = (_Float16*)(smem + 32768);  // 4 x [64 q][40] (32 j + pad)
    _Float16* oscr = (_Float16*)smem;           // reuse: 3 x [64 q][68] f16
    float* lsumBuf = (float*)(smem + 32768);    // reuse: [4][64] f32

    const int tid = threadIdx.x;
    const int w = tid>>6, l = tid&63, lr = l&15, lq = l>>4;
    const int sw = lr&7;
    const int bh = blockIdx.y, q0 = blockIdx.x*64;
    const int b = bh>>3, h = bh&7;
    const _Float16* Qp = Q  + (size_t)bh*SEQ*DHEAD;
    const _Float16* Kp = K  + (size_t)bh*SEQ*DHEAD;
    const _Float16* Vp = VT + (size_t)bh*DHEAD*SEQ;
    _Float16* lPw = lPT + w*2560;

    // staging lane maps (swizzle lives in the global address)
    const int kst_r = (l>>3), kst_c = ((l&7) ^ ((l>>3)&7))*8;
    const int vst_r = (l>>4);

    // Q fragments (B-operand): q = q0 + qg*16 + lr, k = d
    f16x8 qf[4][2];
#pragma unroll
    for (int qg = 0; qg < 4; qg++)
#pragma unroll
        for (int kb = 0; kb < 2; kb++)
            qf[qg][kb] = *(const f16x8*)&Qp[(q0+qg*16+lr)*DHEAD + kb*32 + lq*8];

    fx4 O[4][4] = {};          // [db][qg]; d = db*16+lq*4+i, q = qg*16+lr
    float lsum[4] = {};        // per-lane partial rowsum for q = qg*16+lr

    for (int kt = 0; kt < 8; kt++) {
        int k0 = kt*128;
        __syncthreads();
#pragma unroll
        for (int t = 0; t < 4; t++) {          // K tile [128][64]
            int rbase = w*32 + t*8;
            gload16(&Kp[(size_t)(k0+rbase+kst_r)*DHEAD + kst_c], &lK[rbase*64]);
        }
#pragma unroll
        for (int t = 0; t < 4; t++) {          // VT tile [64][128]
            int rbase = w*16 + t*4;
            int r = rbase + vst_r;
            int g = (l&15) ^ (r&7);
            gload16(&Vp[(size_t)r*SEQ + k0 + g*8], &lVT[rbase*128]);
        }
        __syncthreads();

        // ---- S^T for wave's j-slice; clip+exp; P^T (q-major) to lPw ----
#pragma unroll
        for (int rb2 = 0; rb2 < 2; rb2++) {
            int jrow = w*32 + rb2*16 + lr;
            f16x8 kf0 = *(const f16x8*)&lK[jrow*64 + ((lq^sw))*8];
            f16x8 kf1 = *(const f16x8*)&lK[jrow*64 + (((4+lq)^sw))*8];
#pragma unroll
            for (int qg = 0; qg < 4; qg++) {
                fx4 s = {};
                s = MFMA16(kf0, qf[qg][0], s, 0,0,0);
                s = MFMA16(kf1, qf[qg][1], s, 0,0,0);
                f16x4 p4;
#pragma unroll
                for (int i = 0; i < 4; i++) {
                    float p = __expf(__builtin_amdgcn_fmed3f(s[i], 1e-6f, 1.0f));
                    lsum[qg] += p;
                    p4[i] = (_Float16)p;
                }
                *(f16x4*)&lPw[(qg*16+lr)*40 + rb2*16 + lq*4] = p4;
            }
        }
        // ---- O^T += VT_slice . P (same-wave LDS RAW, no barrier needed) ----
        f16x8 vf[4];
#pragma unroll
        for (int db = 0; db < 4; db++)
            vf[db] = *(const f16x8*)&lVT[(db*16+lr)*128 + (((w*4+lq)^sw))*8];
#pragma unroll
        for (int qg = 0; qg < 4; qg++) {
            f16x8 pf = *(const f16x8*)&lPw[(qg*16+lr)*40 + lq*8];
#pragma unroll
            for (int db = 0; db < 4; db++)
                O[db][qg] = MFMA16(vf[db], pf, O[db][qg], 0,0,0);
        }
    }

    // ---- reductions: lsum over lq-quads, then cross-wave via LDS ----
#pragma unroll
    for (int qg = 0; qg < 4; qg++) {
        lsum[qg] += __shfl_xor(lsum[qg], 16);
        lsum[qg] += __shfl_xor(lsum[qg], 32);
    }
    __syncthreads();                            // kt-loop LDS reads all done
    if (lq == 0) {
#pragma unroll
        for (int qg = 0; qg < 4; qg++)
            lsumBuf[w*64 + qg*16 + lr] = lsum[qg];
    }
    if (w > 0) {
        _Float16* oo = oscr + (w-1)*4352;       // [64 q][68]
#pragma unroll
        for (int db = 0; db < 4; db++)
#pragma unroll
            for (int qg = 0; qg < 4; qg++) {
                f16x4 t;
#pragma unroll
                for (int i = 0; i < 4; i++) t[i] = (_Float16)O[db][qg][i];
                *(f16x4*)&oo[(qg*16+lr)*68 + db*16 + lq*4] = t;
            }
    }
    __syncthreads();
    if (w == 0) {
#pragma unroll
        for (int qg = 0; qg < 4; qg++) {
            float tot = lsum[qg] + lsumBuf[64 + qg*16+lr]
                      + lsumBuf[128 + qg*16+lr] + lsumBuf[192 + qg*16+lr];
            float inv = 1.0f / tot;
            int q = q0 + qg*16 + lr;
            _Float16* aop = AO + ((size_t)(b*SEQ + q)*HEADS + h)*DHEAD;
#pragma unroll
            for (int db = 0; db < 4; db++) {
                fx4 o = O[db][qg];
#pragma unroll
                for (int ww = 1; ww < 4; ww++) {
                    f16x4 t = *(const f16x4*)
                        &oscr[(ww-1)*4352 + (qg*16+lr)*68 + db*16 + lq*4];
#pragma unroll
                    for (int i = 0; i < 4; i++) o[i] += (float)t[i];
                }
                f16x4 r;
#pragma unroll
                for (int i = 0; i < 4; i++) r[i] = (_Float16)(o[i] * inv);
                *(f16x4*)&aop[db*16 + lq*4] = r;
            }
        }
    }
}

// ---------------------------------------------------------------------------
// Kernel 3: output projection  out = AO @ wo^T + bo   (M=8192, N=512, K=512)
// ---------------------------------------------------------------------------
__global__ __launch_bounds__(256,3) void out_proj(
    const _Float16* __restrict__ A, const _Float16* __restrict__ B,
    const float* __restrict__ bo, float* __restrict__ out)
{
    __shared__ _Float16 lA[128*64];
    __shared__ _Float16 lB[128*64];
    const int tid = threadIdx.x;
    const int m0 = blockIdx.y*128, n0 = blockIdx.x*128;
    const int w = tid>>6, l = tid&63, lr = l&15, lq = l>>4;
    const int wr = w>>1, wc = w&1;
    const int srow = (l>>3);
    const int scol = ((l&7) ^ ((l>>3)&7))*8;
    const int sw = lr&7;
    fx4 acc[4][4] = {};

    for (int k0 = 0; k0 < DIM; k0 += 64) {
        __syncthreads();
#pragma unroll
        for (int t = 0; t < 4; t++) {
            int row = w*32 + t*8;
            gload16(&A[(size_t)(m0+row+srow)*DIM + k0 + scol], &lA[row*64]);
            gload16(&B[(size_t)(n0+row+srow)*DIM + k0 + scol], &lB[row*64]);
        }
        __syncthreads();
#pragma unroll
        for (int kb = 0; kb < 2; kb++) {
            f16x8 af[4], bf[4];
#pragma unroll
            for (int cb = 0; cb < 4; cb++)
                bf[cb] = *(const f16x8*)&lB[(wc*64+cb*16+lr)*64 + (((kb*4+lq)^sw))*8];
#pragma unroll
            for (int rb = 0; rb < 4; rb++)
                af[rb] = *(const f16x8*)&lA[(wr*64+rb*16+lr)*64 + (((kb*4+lq)^sw))*8];
#pragma unroll
            for (int rb = 0; rb < 4; rb++)
#pragma unroll
                for (int cb = 0; cb < 4; cb++)
                    acc[rb][cb] = MFMA16(af[rb], bf[cb], acc[rb][cb], 0,0,0);
        }
    }
#pragma unroll
    for (int rb = 0; rb < 4; rb++)
#pragma unroll
        for (int cb = 0; cb < 4; cb++) {
            int nn = n0 + wc*64 + cb*16 + lr;
            float bias = bo[nn];
#pragma unroll
            for (int i = 0; i < 4; i++) {
                int m = m0 + wr*64 + rb*16 + lq*4 + i;
                out[(size_t)m*DIM + nn] = acc[rb][cb][i] + bias;
            }
        }
}

// ---------------------------------------------------------------------------
extern "C" void kernel_launch(void* const* d_in, const int* in_sizes, int n_in,
                              void* d_out, int out_size, void* d_ws, size_t ws_size,
                              hipStream_t stream)
{
    const float* x  = (const float*)d_in[0];
    const float* wq = (const float*)d_in[1];
    const float* wk = (const float*)d_in[2];
    const float* wv = (const float*)d_in[3];
    const float* wo = (const float*)d_in[4];
    const float* bo = (const float*)d_in[5];
    float* out = (float*)d_out;
    char* ws = (char*)d_ws;

    _Float16* xb    = (_Float16*)(ws);              // 8 MB   [8192][512] f16
    _Float16* wqkvb = (_Float16*)(ws + 8388608);    // 1.5 MB [1536][512]
    _Float16* wob   = (_Float16*)(ws + 9961472);    // 0.5 MB [512][512]
    _Float16* Qb    = (_Float16*)(ws + 10485760);   // 8 MB   [b,h,n,d] (pre-scaled)
    _Float16* Kb    = (_Float16*)(ws + 18874368);   // 8 MB   [b,h,n,d]
    _Float16* VTb   = (_Float16*)(ws + 27262976);   // 8 MB   [b,h,d,n]
    _Float16* attnb = (_Float16*)(ws);              // alias xb (x dead after proj)

    convert_k<<<5120, 256, 0, stream>>>(x, wq, wk, wv, wo, xb, wqkvb, wob);
    qkv_proj<<<dim3(12, 64), 256, 0, stream>>>(xb, wqkvb, Qb, Kb, VTb);
    attn_k<<<dim3(16, 64), 256, 0, stream>>>(Qb, Kb, VTb, attnb);
    out_proj<<<dim3(4, 64), 256, 0, stream>>>(attnb, wob, bo, out);
}